// Round 1
// baseline (13642.686 us; speedup 1.0000x reference)
//
#include <hip/hip_runtime.h>
#include <cstdint>

typedef unsigned short u16;
typedef __attribute__((ext_vector_type(8))) short bf16x8;
typedef __attribute__((ext_vector_type(4))) float f32x4;

#define S_LEN 1000
#define NWG   32               // scan workgroups (each owns 16 H-columns)

// ---------------- ws layout (bytes). Total ~68.2 MB ----------------
#define OFF_HALL   0ull                         // (1001*64, 512) bf16 hidden states; xb aliases here (dead before scan)
#define SZ_HALL    (1001ull*64*512*2)
#define OFF_WCAT   (OFF_HALL + SZ_HALL)         // (1536, 448) bf16  [Wh;Wz;Wr] K-padded
#define SZ_WCAT    (1536ull*448*2)
#define OFF_WFB    (OFF_WCAT + SZ_WCAT)         // (1024, 512) bf16  Wf row-padded
#define SZ_WFB     (1024ull*512*2)
#define OFF_RH     (OFF_WFB + SZ_WFB)           // (64,512) bf16  r*h exchange buffer
#define SZ_RH      (64ull*512*2)
#define OFF_GSUM   (OFF_RH + SZ_RH)
#define OFF_GSQ    (OFF_GSUM + 1536*4)
#define OFF_AALL   (OFF_GSQ  + 1536*4)
#define OFF_CALL   (OFF_AALL + 1536*4)
#define OFF_SSUM   (OFF_CALL + 1536*4)
#define OFF_SSQ    (OFF_SSUM + 1024*4)
#define OFF_AF     (OFF_SSQ  + 1024*4)
#define OFF_CF     (OFF_AF   + 1024*4)
#define OFF_FLAGS  (OFF_CF   + 1024*4)
#define STATS_ZERO_BYTES (OFF_FLAGS + 256 - OFF_GSUM)

// ---------------- helpers ----------------
__device__ __forceinline__ float bf2f(u16 u) {
  union { unsigned u; float f; } v; v.u = ((unsigned)u) << 16; return v.f;
}
__device__ __forceinline__ u16 f2bf(float f) {   // RNE
  union { float f; unsigned u; } v; v.f = f;
  unsigned r = (v.u + 0x7fffu + ((v.u >> 16) & 1u)) >> 16;
  return (u16)r;
}
__device__ __forceinline__ float sigm(float x) { return 1.f / (1.f + __expf(-x)); }
__device__ __forceinline__ float tanh_(float x) {
  float e = __expf(-2.f * fabsf(x));
  float r = (1.f - e) / (1.f + e);
  return x >= 0.f ? r : -r;
}

// async global->LDS, 16B/lane; dest = uniform base + lane*16
__device__ __forceinline__ void stage16(const u16* g, u16* l) {
#if defined(__has_builtin) && __has_builtin(__builtin_amdgcn_global_load_lds)
  __builtin_amdgcn_global_load_lds((const __attribute__((address_space(1))) unsigned int*)(g),
                                   (__attribute__((address_space(3))) unsigned int*)(l), 16, 0, 0);
#else
  int lane = threadIdx.x & 63;
  *(bf16x8*)(l + lane * 8) = *(const bf16x8*)(g + lane * 0); // unreachable fallback variant below
#endif
}

// ---------------- fp32 -> bf16 converts with padding ----------------
__global__ void cvt_pad(const float* __restrict__ src, u16* __restrict__ dst, int incols, int outcols) {
  int r = blockIdx.x, ci = threadIdx.x;
  float v = (ci < incols) ? src[(size_t)r * incols + ci] : 0.f;
  dst[(size_t)r * outcols + ci] = f2bf(v);
}
__global__ void cvt_wf(const float* __restrict__ src, u16* __restrict__ dst) {
  int r = blockIdx.x, ci = threadIdx.x;     // grid 1024, block 512; rows >= 1000 are zero pad
  float v = (r < 1000) ? src[(size_t)r * 512 + ci] : 0.f;
  dst[(size_t)r * 512 + ci] = f2bf(v);
}

// ---------------- bf16 GEMM  C[M,N] = A[M,K] @ B[N,K]^T  (128x128 tile, BK=32) ----------------
// LDS block layout per 16-row group: unit l (16B) = (k-chunk l>>4, row l&15) -> staging order == frag-read order.
template<bool F32OUT>
__global__ __launch_bounds__(256, 1) void gemm_bt(const u16* __restrict__ A, const u16* __restrict__ B,
                                                  void* __restrict__ Cout, int K, int ldc, int nlimit) {
  __shared__ __align__(16) u16 smem[16 * 512];  // 8 A-blocks (8KB) + 8 B-blocks (8KB)
  const int bm = blockIdx.x * 128;
  const int bn = blockIdx.y * 128;
  const int tid = threadIdx.x;
  const int w = tid >> 6;
  const int lane = tid & 63;
  const int r = lane & 15;
  const int q = lane >> 4;
  const int wm = w & 1, wn = w >> 1;

  f32x4 acc[4][4];
#pragma unroll
  for (int i = 0; i < 4; ++i)
#pragma unroll
    for (int j = 0; j < 4; ++j) acc[i][j] = (f32x4){0.f, 0.f, 0.f, 0.f};

  const u16* gA0 = A + (size_t)(bm + w * 16 + r) * K + q * 8;
  const u16* gA1 = A + (size_t)(bm + (w + 4) * 16 + r) * K + q * 8;
  const u16* gB0 = B + (size_t)(bn + w * 16 + r) * K + q * 8;
  const u16* gB1 = B + (size_t)(bn + (w + 4) * 16 + r) * K + q * 8;
  u16* As = smem;
  u16* Bs = smem + 8 * 512;

  for (int k0 = 0; k0 < K; k0 += 32) {
    stage16(gA0 + k0, As + w * 512);
    stage16(gA1 + k0, As + (w + 4) * 512);
    stage16(gB0 + k0, Bs + w * 512);
    stage16(gB1 + k0, Bs + (w + 4) * 512);
    __syncthreads();
    bf16x8 af[4], bf_[4];
#pragma unroll
    for (int mi = 0; mi < 4; ++mi) af[mi] = *(const bf16x8*)(As + (wm * 4 + mi) * 512 + lane * 8);
#pragma unroll
    for (int ni = 0; ni < 4; ++ni) bf_[ni] = *(const bf16x8*)(Bs + (wn * 4 + ni) * 512 + lane * 8);
#pragma unroll
    for (int mi = 0; mi < 4; ++mi)
#pragma unroll
      for (int ni = 0; ni < 4; ++ni)
        acc[mi][ni] = __builtin_amdgcn_mfma_f32_16x16x32_bf16(af[mi], bf_[ni], acc[mi][ni], 0, 0, 0);
    __syncthreads();
  }
  const int row0 = bm + wm * 64;
  const int col0 = bn + wn * 64;
#pragma unroll
  for (int mi = 0; mi < 4; ++mi)
#pragma unroll
    for (int ni = 0; ni < 4; ++ni)
#pragma unroll
      for (int i = 0; i < 4; ++i) {
        int rr = row0 + mi * 16 + q * 4 + i;   // C/D: row=(lane>>4)*4+reg, col=lane&15
        int cc = col0 + ni * 16 + r;
        if (F32OUT) {
          if (cc < nlimit) ((float*)Cout)[(size_t)rr * ldc + cc] = acc[mi][ni][i];
        } else {
          ((u16*)Cout)[(size_t)rr * ldc + cc] = f2bf(acc[mi][ni][i]);
        }
      }
}

// ---------------- per-column sum/sumsq over 64000 rows ----------------
template<int BF16IN>
__global__ __launch_bounds__(256, 1) void colstats(const void* __restrict__ Xv, int ld, int ncols,
                                                   float* __restrict__ sum, float* __restrict__ sumsq) {
  const int col = blockIdx.x * 128 + (threadIdx.x & 127);
  const int half = threadIdx.x >> 7;
  const int r0 = blockIdx.y * 2000;
  float s = 0.f, ss = 0.f;
  if (col < ncols) {
    if (BF16IN) {
      const u16* X = (const u16*)Xv;
      for (int rr = r0 + half; rr < r0 + 2000; rr += 2) {
        float v = bf2f(X[(size_t)rr * ld + col]); s += v; ss += v * v;
      }
    } else {
      const float* X = (const float*)Xv;
      for (int rr = r0 + half; rr < r0 + 2000; rr += 2) {
        float v = X[(size_t)rr * ld + col]; s += v; ss += v * v;
      }
    }
  }
  __shared__ float ls[128], lss[128];
  if (half) { ls[threadIdx.x & 127] = s; lss[threadIdx.x & 127] = ss; }
  __syncthreads();
  if (!half && col < ncols) {
    s += ls[threadIdx.x]; ss += lss[threadIdx.x];
    atomicAdd(&sum[col], s); atomicAdd(&sumsq[col], ss);
  }
}

__global__ void fin_gate(const float* __restrict__ sum, const float* __restrict__ sq,
                         const float* gh, const float* bh, const float* gz, const float* bz,
                         const float* gr, const float* br, float* __restrict__ a, float* __restrict__ c) {
  int j = blockIdx.x * 256 + threadIdx.x;
  if (j >= 1536) return;
  float m = sum[j] * (1.f / 64000.f);
  float v = sq[j] * (1.f / 64000.f) - m * m;
  int seg = j >> 9, jj = j & 511;            // cols 0-511: Wh-proj, 512-1023: Wz, 1024-1535: Wr
  float gg = seg == 0 ? gh[jj] : seg == 1 ? gz[jj] : gr[jj];
  float bb = seg == 0 ? bh[jj] : seg == 1 ? bz[jj] : br[jj];
  float aa = gg * rsqrtf(v + 1e-5f);
  a[j] = aa; c[j] = bb - m * aa;
}

__global__ void fin_score(const float* __restrict__ sum, const float* __restrict__ sq,
                          const float* __restrict__ gfp, const float* __restrict__ bfp,
                          float* __restrict__ a, float* __restrict__ c) {
  int j = blockIdx.x * 256 + threadIdx.x;
  if (j >= 1000) return;
  float m = sum[j] * (1.f / 64000.f);
  float v = sq[j] * (1.f / 64000.f) - m * m;
  float aa = gfp[j] * rsqrtf(v + 1e-5f);
  a[j] = aa; c[j] = bfp[j] - m * aa;
}

// ---------------- grid barrier (device scope, monotonic count, epoch release) ----------------
__device__ __forceinline__ void gbar(unsigned* cnt, unsigned* gen, unsigned n) {
  __syncthreads();
  if (threadIdx.x == 0) {
    __builtin_amdgcn_fence(__ATOMIC_RELEASE, "agent");
    unsigned prev = __hip_atomic_fetch_add(cnt, 1u, __ATOMIC_ACQ_REL, __HIP_MEMORY_SCOPE_AGENT);
    if (prev == n * NWG - 1u) {
      __hip_atomic_store(gen, n, __ATOMIC_RELEASE, __HIP_MEMORY_SCOPE_AGENT);
    } else {
      while (__hip_atomic_load(gen, __ATOMIC_ACQUIRE, __HIP_MEMORY_SCOPE_AGENT) < n)
        __builtin_amdgcn_s_sleep(1);
    }
    __builtin_amdgcn_fence(__ATOMIC_ACQUIRE, "agent");
  }
  __syncthreads();
}

// ---------------- persistent GRU scan: 32 WGs, each owns 16 H-columns ----------------
__global__ __launch_bounds__(256, 1) void scan_kernel(
    const u16* __restrict__ gates,               // (64000,1536) bf16 raw projections (in d_out)
    const float* __restrict__ Uz, const float* __restrict__ Ur, const float* __restrict__ Uh,
    const float* __restrict__ acoef, const float* __restrict__ ccoef,
    u16* __restrict__ hall,                      // (1001*64,512) bf16; row t*64+b
    u16* __restrict__ rh,                        // (64,512) bf16
    unsigned* __restrict__ bcnt, unsigned* __restrict__ bgen) {
  __shared__ __align__(16) u16 Us[3][16][520];   // U slices [j][k], +8 pad balances LDS banks
  __shared__ float co[6][16];
  const int g = blockIdx.x;
  const int j0 = g * 16;
  const int tid = threadIdx.x;
  const int w = tid >> 6;         // wave -> batch rows [16w,16w+16)
  const int lane = tid & 63;
  const int r = lane & 15;        // A-frag row / B-frag col / C col
  const int q = lane >> 4;        // k-chunk / C row-quad

  for (int idx = tid; idx < 3 * 16 * 512; idx += 256) {
    int u = idx >> 13;
    int rem = idx & 8191;
    int j = rem >> 9;
    int k = rem & 511;
    const float* U = (u == 0) ? Uz : (u == 1) ? Ur : Uh;
    Us[u][j][k] = f2bf(U[(size_t)(j0 + j) * 512 + k]);
  }
  if (tid < 16) {
    co[0][tid] = acoef[512 + j0 + tid];  co[1][tid] = ccoef[512 + j0 + tid];   // z (Wz cols)
    co[2][tid] = acoef[1024 + j0 + tid]; co[3][tid] = ccoef[1024 + j0 + tid];  // r (Wr cols)
    co[4][tid] = acoef[j0 + tid];        co[5][tid] = ccoef[j0 + tid];         // h (Wh cols)
  }
  __syncthreads();
  const float az = co[0][r], cz = co[1][r], ar = co[2][r], cr = co[3][r];
  const float ah = co[4][r], ch = co[5][r];

  unsigned bn_ = 0;
  for (int t = 1; t <= S_LEN; ++t) {
    const u16* hprev = hall + (size_t)(t - 1) * (64 * 512);
    // ---- phase A: z, r, r*h ----
    f32x4 accz = {0.f, 0.f, 0.f, 0.f}, accr = {0.f, 0.f, 0.f, 0.f};
    const u16* arow = hprev + (size_t)(w * 16 + r) * 512 + q * 8;
#pragma unroll
    for (int ks = 0; ks < 16; ++ks) {
      bf16x8 a = *(const bf16x8*)(arow + ks * 32);
      bf16x8 bz = *(const bf16x8*)(&Us[0][r][ks * 32 + q * 8]);
      bf16x8 br2 = *(const bf16x8*)(&Us[1][r][ks * 32 + q * 8]);
      accz = __builtin_amdgcn_mfma_f32_16x16x32_bf16(a, bz, accz, 0, 0, 0);
      accr = __builtin_amdgcn_mfma_f32_16x16x32_bf16(a, br2, accr, 0, 0, 0);
    }
    const size_t grow = (size_t)(t - 1) * 64 + w * 16 + q * 4;
    float zv[4], rv[4], hp[4];
#pragma unroll
    for (int i = 0; i < 4; ++i) {
      float wz = bf2f(gates[(grow + i) * 1536 + 512 + j0 + r]);
      float wr = bf2f(gates[(grow + i) * 1536 + 1024 + j0 + r]);
      zv[i] = sigm(accz[i] + wz * az + cz);
      rv[i] = sigm(accr[i] + wr * ar + cr);
      hp[i] = bf2f(hprev[(size_t)(w * 16 + q * 4 + i) * 512 + j0 + r]);
      rh[(size_t)(w * 16 + q * 4 + i) * 512 + j0 + r] = f2bf(rv[i] * hp[i]);
    }
    gbar(bcnt, bgen, ++bn_);
    // ---- phase B: hcand, h_t ----
    f32x4 acch = {0.f, 0.f, 0.f, 0.f};
    const u16* rrow = rh + (size_t)(w * 16 + r) * 512 + q * 8;
#pragma unroll
    for (int ks = 0; ks < 16; ++ks) {
      bf16x8 a = *(const bf16x8*)(rrow + ks * 32);
      bf16x8 bh = *(const bf16x8*)(&Us[2][r][ks * 32 + q * 8]);
      acch = __builtin_amdgcn_mfma_f32_16x16x32_bf16(a, bh, acch, 0, 0, 0);
    }
    u16* hnew = hall + (size_t)t * (64 * 512);
#pragma unroll
    for (int i = 0; i < 4; ++i) {
      float wh = bf2f(gates[(grow + i) * 1536 + j0 + r]);
      float hc = tanh_(acch[i] + wh * ah + ch);
      float hn = zv[i] * hp[i] + (1.f - zv[i]) * hc;
      hnew[(size_t)(w * 16 + q * 4 + i) * 512 + j0 + r] = f2bf(hn);
    }
    gbar(bcnt, bgen, ++bn_);
  }
}

// ---------------- BN + log_softmax, in place on fp32 scores ----------------
__global__ __launch_bounds__(256, 1) void logsoftmax_k(float* __restrict__ S,
                                                       const float* __restrict__ a, const float* __restrict__ c) {
  __shared__ float as_[1000], cs_[1000];
  for (int i = threadIdx.x; i < 1000; i += 256) { as_[i] = a[i]; cs_[i] = c[i]; }
  __syncthreads();
  const int w = threadIdx.x >> 6, lane = threadIdx.x & 63;
  for (int it = 0; it < 4; ++it) {
    const int row = blockIdx.x * 16 + it * 4 + w;
    float* Srow = S + (size_t)row * 1000;
    float tv[16];
    float mx = -3.0e38f;
#pragma unroll
    for (int qq = 0; qq < 16; ++qq) {
      int j = lane + qq * 64;
      float v = -3.0e38f;
      if (j < 1000) v = as_[j] * Srow[j] + cs_[j];
      tv[qq] = v;
      mx = fmaxf(mx, v);
    }
#pragma unroll
    for (int o = 32; o > 0; o >>= 1) mx = fmaxf(mx, __shfl_xor(mx, o));
    float sm = 0.f;
#pragma unroll
    for (int qq = 0; qq < 16; ++qq) sm += __expf(tv[qq] - mx);
#pragma unroll
    for (int o = 32; o > 0; o >>= 1) sm += __shfl_xor(sm, o);
    float lse = mx + __logf(sm);
#pragma unroll
    for (int qq = 0; qq < 16; ++qq) {
      int j = lane + qq * 64;
      if (j < 1000) Srow[j] = tv[qq] - lse;
    }
  }
}

// ---------------- launch ----------------
extern "C" void kernel_launch(void* const* d_in, const int* in_sizes, int n_in,
                              void* d_out, int out_size, void* d_ws, size_t ws_size,
                              hipStream_t stream) {
  const float* x  = (const float*)d_in[0];
  const float* Wh = (const float*)d_in[1];
  const float* Wz = (const float*)d_in[2];
  const float* Wr = (const float*)d_in[3];
  const float* Uh = (const float*)d_in[4];
  const float* Uz = (const float*)d_in[5];
  const float* Ur = (const float*)d_in[6];
  const float* gh = (const float*)d_in[7];
  const float* bh = (const float*)d_in[8];
  const float* gz = (const float*)d_in[9];
  const float* bz = (const float*)d_in[10];
  const float* gr = (const float*)d_in[11];
  const float* br = (const float*)d_in[12];
  const float* Wf = (const float*)d_in[13];
  const float* gf = (const float*)d_in[14];
  const float* bfp = (const float*)d_in[15];

  uint8_t* ws = (uint8_t*)d_ws;
  u16* hall = (u16*)(ws + OFF_HALL);
  u16* xb   = (u16*)(ws + OFF_HALL);   // alias: xb dead before hall is written
  u16* wcat = (u16*)(ws + OFF_WCAT);
  u16* wfb  = (u16*)(ws + OFF_WFB);
  u16* rh   = (u16*)(ws + OFF_RH);
  float* gsum = (float*)(ws + OFF_GSUM);
  float* gsq  = (float*)(ws + OFF_GSQ);
  float* aall = (float*)(ws + OFF_AALL);
  float* call = (float*)(ws + OFF_CALL);
  float* ssum = (float*)(ws + OFF_SSUM);
  float* ssq  = (float*)(ws + OFF_SSQ);
  float* af   = (float*)(ws + OFF_AF);
  float* cf   = (float*)(ws + OFF_CF);
  unsigned* flags = (unsigned*)(ws + OFF_FLAGS);  // [0]=count, [32]=generation (separate lines)

  u16* gates = (u16*)d_out;      // (64000,1536) bf16, dead after scan
  float* scores = (float*)d_out; // (64000,1000) fp32, written by classifier GEMM

  hipMemsetAsync(ws + OFF_GSUM, 0, (size_t)STATS_ZERO_BYTES, stream);

  cvt_pad<<<dim3(64000), dim3(448), 0, stream>>>(x, xb, 440, 448);
  cvt_pad<<<dim3(512), dim3(448), 0, stream>>>(Wh, wcat, 440, 448);
  cvt_pad<<<dim3(512), dim3(448), 0, stream>>>(Wz, wcat + 512 * 448, 440, 448);
  cvt_pad<<<dim3(512), dim3(448), 0, stream>>>(Wr, wcat + 1024 * 448, 440, 448);
  cvt_wf<<<dim3(1024), dim3(512), 0, stream>>>(Wf, wfb);

  gemm_bt<false><<<dim3(500, 12), dim3(256), 0, stream>>>(xb, wcat, (void*)gates, 448, 1536, 1536);

  colstats<1><<<dim3(12, 32), dim3(256), 0, stream>>>((const void*)gates, 1536, 1536, gsum, gsq);
  fin_gate<<<dim3(6), dim3(256), 0, stream>>>(gsum, gsq, gh, bh, gz, bz, gr, br, aall, call);

  hipMemsetAsync(ws + OFF_HALL, 0, (size_t)(64 * 512 * 2), stream);  // h_0 = 0 (after K1 read xb rows)

  scan_kernel<<<dim3(NWG), dim3(256), 0, stream>>>(gates, Uz, Ur, Uh, aall, call, hall, rh,
                                                   flags, flags + 32);

  gemm_bt<true><<<dim3(500, 8), dim3(256), 0, stream>>>(hall + 64 * 512, wfb, (void*)scores, 512, 1000, 1000);

  colstats<0><<<dim3(8, 32), dim3(256), 0, stream>>>((const void*)scores, 1000, 1000, ssum, ssq);
  fin_score<<<dim3(4), dim3(256), 0, stream>>>(ssum, ssq, gf, bfp, af, cf);

  logsoftmax_k<<<dim3(4000), dim3(256), 0, stream>>>(scores, af, cf);
}

// Round 2
// 12513.361 us; speedup vs baseline: 1.0902x; 1.0902x over previous
//
#include <hip/hip_runtime.h>
#include <cstdint>

typedef unsigned short u16;
typedef unsigned long long u64;
typedef __attribute__((ext_vector_type(8))) short bf16x8;
typedef __attribute__((ext_vector_type(4))) float f32x4;

#define S_LEN 1000
#define NWG   32               // scan workgroups (each owns 16 H-columns)

// ---------------- ws layout (bytes) ----------------
#define OFF_HALL   0ull                         // (1001*64, 512) bf16 hidden states; xb aliases here (dead before scan)
#define SZ_HALL    (1001ull*64*512*2)
#define OFF_WCAT   (OFF_HALL + SZ_HALL)         // (1536, 448) bf16  [Wh;Wz;Wr] K-padded
#define SZ_WCAT    (1536ull*448*2)
#define OFF_WFB    (OFF_WCAT + SZ_WCAT)         // (1024, 512) bf16  Wf row-padded
#define SZ_WFB     (1024ull*512*2)
#define OFF_RH     (OFF_WFB + SZ_WFB)           // (64,512) bf16  r*h exchange buffer
#define SZ_RH      (64ull*512*2)
#define OFF_GSUM   (OFF_RH + SZ_RH)
#define OFF_GSQ    (OFF_GSUM + 1536*4)
#define OFF_AALL   (OFF_GSQ  + 1536*4)
#define OFF_CALL   (OFF_AALL + 1536*4)
#define OFF_SSUM   (OFF_CALL + 1536*4)
#define OFF_SSQ    (OFF_SSUM + 1024*4)
#define OFF_AF     (OFF_SSQ  + 1024*4)
#define OFF_CF     (OFF_AF   + 1024*4)
#define OFF_FLAGS  (OFF_CF   + 1024*4)          // 32 flags, 64B apart
#define STATS_ZERO_BYTES (OFF_FLAGS + 2048 - OFF_SSUM)

// ---------------- helpers ----------------
__device__ __forceinline__ float bf2f(u16 u) {
  union { unsigned u; float f; } v; v.u = ((unsigned)u) << 16; return v.f;
}
__device__ __forceinline__ u16 f2bf(float f) {   // RNE
  union { float f; unsigned u; } v; v.f = f;
  unsigned r = (v.u + 0x7fffu + ((v.u >> 16) & 1u)) >> 16;
  return (u16)r;
}
__device__ __forceinline__ float sigm(float x) { return 1.f / (1.f + __expf(-x)); }
__device__ __forceinline__ float tanh_(float x) {
  float e = __expf(-2.f * fabsf(x));
  float r = (1.f - e) / (1.f + e);
  return x >= 0.f ? r : -r;
}

// LLC-coherent (device-scope, no-fence) exchange primitives: lower to sc0 sc1 ops
__device__ __forceinline__ u64 ld8(const u16* p) {
  return __hip_atomic_load((const u64*)p, __ATOMIC_RELAXED, __HIP_MEMORY_SCOPE_AGENT);
}
__device__ __forceinline__ void st4(u16* p, unsigned v) {
  __hip_atomic_store((unsigned*)p, v, __ATOMIC_RELAXED, __HIP_MEMORY_SCOPE_AGENT);
}
union Frag { u64 q[2]; bf16x8 v; };

// async global->LDS, 16B/lane
__device__ __forceinline__ void stage16(const u16* g, u16* l) {
  __builtin_amdgcn_global_load_lds((const __attribute__((address_space(1))) unsigned int*)(g),
                                   (__attribute__((address_space(3))) unsigned int*)(l), 16, 0, 0);
}

// ---------------- fp32 -> bf16 converts with padding ----------------
__global__ void cvt_pad(const float* __restrict__ src, u16* __restrict__ dst, int incols, int outcols) {
  int r = blockIdx.x, ci = threadIdx.x;
  float v = (ci < incols) ? src[(size_t)r * incols + ci] : 0.f;
  dst[(size_t)r * outcols + ci] = f2bf(v);
}
__global__ void cvt_wf(const float* __restrict__ src, u16* __restrict__ dst) {
  int r = blockIdx.x, ci = threadIdx.x;     // grid 1024, block 512; rows >= 1000 are zero pad
  float v = (r < 1000) ? src[(size_t)r * 512 + ci] : 0.f;
  dst[(size_t)r * 512 + ci] = f2bf(v);
}

// ---------------- bf16 GEMM  C = A[M,K] @ B[N,K]^T  (128x128 tile, BK=32) ----------------
// MODE 1: fp32 row-major C[M,ldc], cols < nlimit.  MODE 2: bf16 transposed C[N][ldc=Mtotal].
template<int MODE>
__global__ __launch_bounds__(256, 1) void gemm_bt(const u16* __restrict__ A, const u16* __restrict__ B,
                                                  void* __restrict__ Cout, int K, int ldc, int nlimit) {
  __shared__ __align__(16) u16 smem[16 * 512];
  const int bm = blockIdx.x * 128;
  const int bn = blockIdx.y * 128;
  const int tid = threadIdx.x;
  const int w = tid >> 6;
  const int lane = tid & 63;
  const int r = lane & 15;
  const int q = lane >> 4;
  const int wm = w & 1, wn = w >> 1;

  f32x4 acc[4][4];
#pragma unroll
  for (int i = 0; i < 4; ++i)
#pragma unroll
    for (int j = 0; j < 4; ++j) acc[i][j] = (f32x4){0.f, 0.f, 0.f, 0.f};

  const u16* gA0 = A + (size_t)(bm + w * 16 + r) * K + q * 8;
  const u16* gA1 = A + (size_t)(bm + (w + 4) * 16 + r) * K + q * 8;
  const u16* gB0 = B + (size_t)(bn + w * 16 + r) * K + q * 8;
  const u16* gB1 = B + (size_t)(bn + (w + 4) * 16 + r) * K + q * 8;
  u16* As = smem;
  u16* Bs = smem + 8 * 512;

  for (int k0 = 0; k0 < K; k0 += 32) {
    stage16(gA0 + k0, As + w * 512);
    stage16(gA1 + k0, As + (w + 4) * 512);
    stage16(gB0 + k0, Bs + w * 512);
    stage16(gB1 + k0, Bs + (w + 4) * 512);
    __syncthreads();
    bf16x8 af[4], bf_[4];
#pragma unroll
    for (int mi = 0; mi < 4; ++mi) af[mi] = *(const bf16x8*)(As + (wm * 4 + mi) * 512 + lane * 8);
#pragma unroll
    for (int ni = 0; ni < 4; ++ni) bf_[ni] = *(const bf16x8*)(Bs + (wn * 4 + ni) * 512 + lane * 8);
#pragma unroll
    for (int mi = 0; mi < 4; ++mi)
#pragma unroll
      for (int ni = 0; ni < 4; ++ni)
        acc[mi][ni] = __builtin_amdgcn_mfma_f32_16x16x32_bf16(af[mi], bf_[ni], acc[mi][ni], 0, 0, 0);
    __syncthreads();
  }
  const int row0 = bm + wm * 64;
  const int col0 = bn + wn * 64;
#pragma unroll
  for (int mi = 0; mi < 4; ++mi)
#pragma unroll
    for (int ni = 0; ni < 4; ++ni) {
      int cc = col0 + ni * 16 + r;            // C/D: col=lane&15, row=(lane>>4)*4+reg
      int rr = row0 + mi * 16 + q * 4;
      if (MODE == 1) {
#pragma unroll
        for (int i = 0; i < 4; ++i)
          if (cc < nlimit) ((float*)Cout)[(size_t)(rr + i) * ldc + cc] = acc[mi][ni][i];
      } else {  // transposed bf16: CT[cc][rr..rr+3] as one 8B store
        u64 pk = (u64)f2bf(acc[mi][ni][0]) | ((u64)f2bf(acc[mi][ni][1]) << 16) |
                 ((u64)f2bf(acc[mi][ni][2]) << 32) | ((u64)f2bf(acc[mi][ni][3]) << 48);
        *(u64*)((u16*)Cout + (size_t)cc * ldc + rr) = pk;
      }
    }
}

// ---------------- per-row sum/sumsq over gatesT (1536 rows x 64000), contiguous ----------------
__global__ __launch_bounds__(256, 1) void rowstats(const u16* __restrict__ G,
                                                   float* __restrict__ sum, float* __restrict__ sumsq) {
  const int n = blockIdx.x;
  const u16* row = G + (size_t)n * 64000;
  float s = 0.f, ss = 0.f;
  for (int idx = threadIdx.x * 8; idx < 64000; idx += 2048) {
    union { bf16x8 v; u16 e[8]; } u;
    u.v = *(const bf16x8*)(row + idx);
#pragma unroll
    for (int e = 0; e < 8; ++e) { float f = bf2f(u.e[e]); s += f; ss += f * f; }
  }
#pragma unroll
  for (int o = 32; o > 0; o >>= 1) { s += __shfl_xor(s, o); ss += __shfl_xor(ss, o); }
  __shared__ float ls[4], lss[4];
  if ((threadIdx.x & 63) == 0) { ls[threadIdx.x >> 6] = s; lss[threadIdx.x >> 6] = ss; }
  __syncthreads();
  if (threadIdx.x == 0) {
    sum[n]   = ls[0] + ls[1] + ls[2] + ls[3];
    sumsq[n] = lss[0] + lss[1] + lss[2] + lss[3];
  }
}

// ---------------- per-column sum/sumsq over fp32 scores (64000 x 1000) ----------------
__global__ __launch_bounds__(256, 1) void colstats_f32(const float* __restrict__ X, int ld, int ncols,
                                                       float* __restrict__ sum, float* __restrict__ sumsq) {
  const int col = blockIdx.x * 128 + (threadIdx.x & 127);
  const int half = threadIdx.x >> 7;
  const int r0 = blockIdx.y * 2000;
  float s = 0.f, ss = 0.f;
  if (col < ncols) {
    for (int rr = r0 + half; rr < r0 + 2000; rr += 2) {
      float v = X[(size_t)rr * ld + col]; s += v; ss += v * v;
    }
  }
  __shared__ float ls[128], lss[128];
  if (half) { ls[threadIdx.x & 127] = s; lss[threadIdx.x & 127] = ss; }
  __syncthreads();
  if (!half && col < ncols) {
    s += ls[threadIdx.x]; ss += lss[threadIdx.x];
    atomicAdd(&sum[col], s); atomicAdd(&sumsq[col], ss);
  }
}

__global__ void fin_gate(const float* __restrict__ sum, const float* __restrict__ sq,
                         const float* gh, const float* bh, const float* gz, const float* bz,
                         const float* gr, const float* br, float* __restrict__ a, float* __restrict__ c) {
  int j = blockIdx.x * 256 + threadIdx.x;
  if (j >= 1536) return;
  float m = sum[j] * (1.f / 64000.f);
  float v = sq[j] * (1.f / 64000.f) - m * m;
  int seg = j >> 9, jj = j & 511;
  float gg = seg == 0 ? gh[jj] : seg == 1 ? gz[jj] : gr[jj];
  float bb = seg == 0 ? bh[jj] : seg == 1 ? bz[jj] : br[jj];
  float aa = gg * rsqrtf(v + 1e-5f);
  a[j] = aa; c[j] = bb - m * aa;
}

__global__ void fin_score(const float* __restrict__ sum, const float* __restrict__ sq,
                          const float* __restrict__ gfp, const float* __restrict__ bfp,
                          float* __restrict__ a, float* __restrict__ c) {
  int j = blockIdx.x * 256 + threadIdx.x;
  if (j >= 1000) return;
  float m = sum[j] * (1.f / 64000.f);
  float v = sq[j] * (1.f / 64000.f) - m * m;
  float aa = gfp[j] * rsqrtf(v + 1e-5f);
  a[j] = aa; c[j] = bfp[j] - m * aa;
}

// ---------------- fence-free flag barrier: drain own stores, publish, poll all ----------------
__device__ __forceinline__ void publish_and_wait(unsigned* flags, int g, unsigned val) {
  asm volatile("s_waitcnt vmcnt(0)" ::: "memory");   // own sc0sc1 stores are at LLC
  __syncthreads();
  if (threadIdx.x == 0)
    __hip_atomic_store(&flags[g * 16], val, __ATOMIC_RELAXED, __HIP_MEMORY_SCOPE_AGENT);
  if (threadIdx.x < 64) {
    const int l = threadIdx.x;
    for (;;) {
      unsigned v = (l < NWG) ? __hip_atomic_load(&flags[l * 16], __ATOMIC_RELAXED, __HIP_MEMORY_SCOPE_AGENT)
                             : val;
      if (__all(v >= val)) break;
      __builtin_amdgcn_s_sleep(1);
    }
  }
  __syncthreads();
  asm volatile("" ::: "memory");
}

// ---------------- persistent GRU scan: 32 WGs, each owns 16 H-columns ----------------
__global__ __launch_bounds__(256, 1) void scan_kernel(
    const u16* __restrict__ gatesT,              // (1536, 64000) bf16 transposed projections (in d_out)
    const float* __restrict__ Uz, const float* __restrict__ Ur, const float* __restrict__ Uh,
    const float* __restrict__ acoef, const float* __restrict__ ccoef,
    u16* __restrict__ hall,                      // (1001*64,512) bf16; row t*64+b
    u16* __restrict__ rh,                        // (64,512) bf16
    unsigned* __restrict__ flags) {
  __shared__ __align__(16) u16 Us[3][16][520];
  __shared__ float co[6][16];
  const int g = blockIdx.x;
  const int j0 = g * 16;
  const int tid = threadIdx.x;
  const int w = tid >> 6;         // wave -> batch rows [16w,16w+16)
  const int lane = tid & 63;
  const int r = lane & 15;
  const int q = lane >> 4;

  for (int idx = tid; idx < 3 * 16 * 512; idx += 256) {
    int u = idx >> 13;
    int rem = idx & 8191;
    int j = rem >> 9;
    int k = rem & 511;
    const float* U = (u == 0) ? Uz : (u == 1) ? Ur : Uh;
    Us[u][j][k] = f2bf(U[(size_t)(j0 + j) * 512 + k]);
  }
  if (tid < 16) {
    co[0][tid] = acoef[512 + j0 + tid];  co[1][tid] = ccoef[512 + j0 + tid];   // z
    co[2][tid] = acoef[1024 + j0 + tid]; co[3][tid] = ccoef[1024 + j0 + tid];  // r
    co[4][tid] = acoef[j0 + tid];        co[5][tid] = ccoef[j0 + tid];         // h
  }
  __syncthreads();
  const float az = co[0][r], cz = co[1][r], ar = co[2][r], cr = co[3][r];
  const float ah = co[4][r], ch = co[5][r];

  // gate rows for this lane (transposed layout: row j, 64000 columns = (t-1)*64 + b)
  const u16* gRowH = gatesT + (size_t)(j0 + r) * 64000;
  const u16* gRowZ = gatesT + (size_t)(512 + j0 + r) * 64000;
  const u16* gRowR = gatesT + (size_t)(1024 + j0 + r) * 64000;

  float hp[4] = {0.f, 0.f, 0.f, 0.f};   // own h slice: rows w*16+q*4+i, col j0+r

  for (int t = 1; t <= S_LEN; ++t) {
    const int ct = (t - 1) * 64 + w * 16 + q * 4;
    // early plain loads of this step's gates (hide behind prior wait / MFMA)
    const u64 wzq = *(const u64*)(gRowZ + ct);
    const u64 wrq = *(const u64*)(gRowR + ct);
    const u64 whq = *(const u64*)(gRowH + ct);

    // ---- phase A: z, r, r*h ----
    const u16* hprev = hall + (size_t)(t - 1) * (64 * 512);
    f32x4 accz = {0.f, 0.f, 0.f, 0.f}, accr = {0.f, 0.f, 0.f, 0.f};
    const u16* arow = hprev + (size_t)(w * 16 + r) * 512 + q * 8;
#pragma unroll
    for (int ks = 0; ks < 16; ++ks) {
      Frag a; a.q[0] = ld8(arow + ks * 32); a.q[1] = ld8(arow + ks * 32 + 4);
      bf16x8 bz = *(const bf16x8*)(&Us[0][r][ks * 32 + q * 8]);
      bf16x8 br2 = *(const bf16x8*)(&Us[1][r][ks * 32 + q * 8]);
      accz = __builtin_amdgcn_mfma_f32_16x16x32_bf16(a.v, bz, accz, 0, 0, 0);
      accr = __builtin_amdgcn_mfma_f32_16x16x32_bf16(a.v, br2, accr, 0, 0, 0);
    }
    float zv[4];
#pragma unroll
    for (int i = 0; i < 4; ++i) {
      float wz = bf2f((u16)(wzq >> (16 * i)));
      float wr = bf2f((u16)(wrq >> (16 * i)));
      zv[i] = sigm(accz[i] + wz * az + cz);
      float rv = sigm(accr[i] + wr * ar + cr);
      u16 rhb = f2bf(rv * hp[i]);
      float partner = __shfl_xor(bf2f(rhb), 1);      // lane r^1's value
      if ((r & 1) == 0)
        st4(rh + (size_t)(w * 16 + q * 4 + i) * 512 + j0 + r,
            (unsigned)rhb | ((unsigned)f2bf(partner) << 16));
    }
    publish_and_wait(flags, g, 2 * t - 1);

    // ---- phase B: hcand, h_t ----
    f32x4 acch = {0.f, 0.f, 0.f, 0.f};
    const u16* rrow = rh + (size_t)(w * 16 + r) * 512 + q * 8;
#pragma unroll
    for (int ks = 0; ks < 16; ++ks) {
      Frag a; a.q[0] = ld8(rrow + ks * 32); a.q[1] = ld8(rrow + ks * 32 + 4);
      bf16x8 bh = *(const bf16x8*)(&Us[2][r][ks * 32 + q * 8]);
      acch = __builtin_amdgcn_mfma_f32_16x16x32_bf16(a.v, bh, acch, 0, 0, 0);
    }
    u16* hnew = hall + (size_t)t * (64 * 512);
#pragma unroll
    for (int i = 0; i < 4; ++i) {
      float wh = bf2f((u16)(whq >> (16 * i)));
      float hc = tanh_(acch[i] + wh * ah + ch);
      float hn = zv[i] * hp[i] + (1.f - zv[i]) * hc;
      u16 hb = f2bf(hn);
      hp[i] = bf2f(hb);                              // carry own slice (bf16-rounded)
      float partner = __shfl_xor(hp[i], 1);
      if ((r & 1) == 0)
        st4(hnew + (size_t)(w * 16 + q * 4 + i) * 512 + j0 + r,
            (unsigned)hb | ((unsigned)f2bf(partner) << 16));
    }
    publish_and_wait(flags, g, 2 * t);
  }
}

// ---------------- BN + log_softmax, in place on fp32 scores ----------------
__global__ __launch_bounds__(256, 1) void logsoftmax_k(float* __restrict__ S,
                                                       const float* __restrict__ a, const float* __restrict__ c) {
  __shared__ float as_[1000], cs_[1000];
  for (int i = threadIdx.x; i < 1000; i += 256) { as_[i] = a[i]; cs_[i] = c[i]; }
  __syncthreads();
  const int w = threadIdx.x >> 6, lane = threadIdx.x & 63;
  for (int it = 0; it < 4; ++it) {
    const int row = blockIdx.x * 16 + it * 4 + w;
    float* Srow = S + (size_t)row * 1000;
    float tv[16];
    float mx = -3.0e38f;
#pragma unroll
    for (int qq = 0; qq < 16; ++qq) {
      int j = lane + qq * 64;
      float v = -3.0e38f;
      if (j < 1000) v = as_[j] * Srow[j] + cs_[j];
      tv[qq] = v;
      mx = fmaxf(mx, v);
    }
#pragma unroll
    for (int o = 32; o > 0; o >>= 1) mx = fmaxf(mx, __shfl_xor(mx, o));
    float sm = 0.f;
#pragma unroll
    for (int qq = 0; qq < 16; ++qq) sm += __expf(tv[qq] - mx);
#pragma unroll
    for (int o = 32; o > 0; o >>= 1) sm += __shfl_xor(sm, o);
    float lse = mx + __logf(sm);
#pragma unroll
    for (int qq = 0; qq < 16; ++qq) {
      int j = lane + qq * 64;
      if (j < 1000) Srow[j] = tv[qq] - lse;
    }
  }
}

// ---------------- launch ----------------
extern "C" void kernel_launch(void* const* d_in, const int* in_sizes, int n_in,
                              void* d_out, int out_size, void* d_ws, size_t ws_size,
                              hipStream_t stream) {
  const float* x  = (const float*)d_in[0];
  const float* Wh = (const float*)d_in[1];
  const float* Wz = (const float*)d_in[2];
  const float* Wr = (const float*)d_in[3];
  const float* Uh = (const float*)d_in[4];
  const float* Uz = (const float*)d_in[5];
  const float* Ur = (const float*)d_in[6];
  const float* gh = (const float*)d_in[7];
  const float* bh = (const float*)d_in[8];
  const float* gz = (const float*)d_in[9];
  const float* bz = (const float*)d_in[10];
  const float* gr = (const float*)d_in[11];
  const float* br = (const float*)d_in[12];
  const float* Wf = (const float*)d_in[13];
  const float* gf = (const float*)d_in[14];
  const float* bfp = (const float*)d_in[15];

  uint8_t* ws = (uint8_t*)d_ws;
  u16* hall = (u16*)(ws + OFF_HALL);
  u16* xb   = (u16*)(ws + OFF_HALL);   // alias: xb dead before hall is written
  u16* wcat = (u16*)(ws + OFF_WCAT);
  u16* wfb  = (u16*)(ws + OFF_WFB);
  u16* rh   = (u16*)(ws + OFF_RH);
  float* gsum = (float*)(ws + OFF_GSUM);
  float* gsq  = (float*)(ws + OFF_GSQ);
  float* aall = (float*)(ws + OFF_AALL);
  float* call = (float*)(ws + OFF_CALL);
  float* ssum = (float*)(ws + OFF_SSUM);
  float* ssq  = (float*)(ws + OFF_SSQ);
  float* af   = (float*)(ws + OFF_AF);
  float* cf   = (float*)(ws + OFF_CF);
  unsigned* flags = (unsigned*)(ws + OFF_FLAGS);

  u16* gatesT = (u16*)d_out;     // (1536, 64000) bf16, dead after scan
  float* scores = (float*)d_out; // (64000,1000) fp32, written by classifier GEMM

  hipMemsetAsync(ws + OFF_SSUM, 0, (size_t)STATS_ZERO_BYTES, stream);

  cvt_pad<<<dim3(64000), dim3(448), 0, stream>>>(x, xb, 440, 448);
  cvt_pad<<<dim3(512), dim3(448), 0, stream>>>(Wh, wcat, 440, 448);
  cvt_pad<<<dim3(512), dim3(448), 0, stream>>>(Wz, wcat + 512 * 448, 440, 448);
  cvt_pad<<<dim3(512), dim3(448), 0, stream>>>(Wr, wcat + 1024 * 448, 440, 448);
  cvt_wf<<<dim3(1024), dim3(512), 0, stream>>>(Wf, wfb);

  gemm_bt<2><<<dim3(500, 12), dim3(256), 0, stream>>>(xb, wcat, (void*)gatesT, 448, 64000, 1536);

  rowstats<<<dim3(1536), dim3(256), 0, stream>>>(gatesT, gsum, gsq);
  fin_gate<<<dim3(6), dim3(256), 0, stream>>>(gsum, gsq, gh, bh, gz, bz, gr, br, aall, call);

  hipMemsetAsync(ws + OFF_HALL, 0, (size_t)(64 * 512 * 2), stream);  // h_0 = 0 (after GEMM read xb rows)

  scan_kernel<<<dim3(NWG), dim3(256), 0, stream>>>(gatesT, Uz, Ur, Uh, aall, call, hall, rh, flags);

  gemm_bt<1><<<dim3(500, 8), dim3(256), 0, stream>>>(hall + 64 * 512, wfb, (void*)scores, 512, 1000, 1000);

  colstats_f32<<<dim3(8, 32), dim3(256), 0, stream>>>(scores, 1000, 1000, ssum, ssq);
  fin_score<<<dim3(4), dim3(256), 0, stream>>>(ssum, ssq, gf, bfp, af, cf);

  logsoftmax_k<<<dim3(4000), dim3(256), 0, stream>>>(scores, af, cf);
}